// Round 14
// baseline (217.637 us; speedup 1.0000x reference)
//
#include <hip/hip_runtime.h>
#include <type_traits>

// ---------------------------------------------------------------------------
// 3-layer GCN, mixed-precision H pipeline with dinv pre-scaling:
//   GEMM (MFMA bf16, fp32 accum) epilogue scales row r by dinv[r]:
//     layers 1,2 -> H' stored FP8 e4m3 (6.4MB gather payload);
//     layer 3 -> H' bf16 (error budget: L3 noise only attenuated once).
//   agg: out[d] = dinv[d]*( sum_e H'[s] + H'[d] ) + b
// Aggregation: 4 nodes/wave (16 lanes/row), padded slots (pad -> zero row n),
// x8 unroll, uint16 indices 8-per-uint4-load (PREFETCHED one iteration ahead
// -> idx load off the dependent chain), HW cvt_pk_f32_fp8 decode.
// Round 13's agg+gemm fusion REVERTED (52KB LDS -> 18% occupancy -> gather
// lost latency hiding; 58us vs 38us unfused. Fused FETCH 49.5MB confirmed
// the 51MB per-XCD replication floor model.)
// 9 dispatches: bin+wtrans+padzero | sizes | place(self-scan) | 3x(gemm,agg).
// ---------------------------------------------------------------------------

#define EPB  4096   // edges per bin block
#define DIRW 197    // directory row width = max buckets (50176/256) + 1

typedef __attribute__((ext_vector_type(8))) short bf16x8;
typedef __attribute__((ext_vector_type(4))) float f32x4;
typedef __attribute__((ext_vector_type(2))) float f32x2;

__device__ __forceinline__ unsigned short f2bf(float f) {
    unsigned int u = __float_as_uint(f);
    u += 0x7FFFu + ((u >> 16) & 1u);   // round-to-nearest-even
    return (unsigned short)(u >> 16);
}
__device__ __forceinline__ float bflo(unsigned int u) { return __uint_as_float(u << 16); }
__device__ __forceinline__ float bfhi(unsigned int u) { return __uint_as_float(u & 0xFFFF0000u); }

// --- Stage 1 (fused): blocks [0,NB) bucket-sort edges; blocks [NB,NB+160)
// pre-transpose W fp32 [k][n] -> bf16 [n][128]; block NB also zeroes pad row.
__global__ __launch_bounds__(256) void bin_wtrans_kernel(const int* __restrict__ src,
                                                         const int* __restrict__ dst,
                                                         unsigned int* __restrict__ pair_buf,
                                                         int* __restrict__ dir,
                                                         int E, int nbkt, int NB,
                                                         const float* __restrict__ W1,
                                                         const float* __restrict__ W2,
                                                         const float* __restrict__ W3,
                                                         unsigned short* __restrict__ Wt1,
                                                         unsigned short* __restrict__ Wt2,
                                                         unsigned short* __restrict__ Wt3,
                                                         unsigned int* __restrict__ hb_pad_row) {
    int blk = blockIdx.x;
    if (blk >= NB) {
        int wb = blk - NB;
        const float* W; unsigned short* Wt; int N, e0;
        if (wb < 64)       { W = W1; Wt = Wt1; N = 128; e0 = wb * 256; }
        else if (wb < 128) { W = W2; Wt = Wt2; N = 128; e0 = (wb - 64) * 256; }
        else               { W = W3; Wt = Wt3; N = 64;  e0 = (wb - 128) * 256; }
        int e = e0 + threadIdx.x;          // output-linear: e = nn*128 + k
        int nn = e >> 7, k = e & 127;
        Wt[e] = f2bf(W[(size_t)k * N + nn]);
        if (wb == 0 && threadIdx.x < 32) hb_pad_row[threadIdx.x] = 0u;  // 128B zero row
        return;
    }
    __shared__ unsigned int stage[EPB];  // 16 KB
    __shared__ int hist[DIRW];
    __shared__ int sc[256];
    __shared__ int cur[DIRW];
    int tid = threadIdx.x;
    if (tid < DIRW) hist[tid] = 0;
    __syncthreads();

    int s_reg[16], d_reg[16];
#pragma unroll
    for (int j = 0; j < 16; ++j) {
        int gi = blk * EPB + j * 256 + tid;
        int s = 0, d = nbkt << 8;          // invalid -> trash bucket nbkt
        if (gi < E) { s = src[gi]; d = dst[gi]; }
        s_reg[j] = s; d_reg[j] = d;
        atomicAdd(&hist[d >> 8], 1);
    }
    __syncthreads();
    int h = (tid < DIRW) ? hist[tid] : 0;
    sc[tid] = h;
    __syncthreads();
#pragma unroll
    for (int off = 1; off < 256; off <<= 1) {
        int v = (tid >= off) ? sc[tid - off] : 0;
        __syncthreads();
        sc[tid] += v;
        __syncthreads();
    }
    if (tid < DIRW) {
        int st = sc[tid] - h;
        cur[tid] = st;
        dir[blk * DIRW + tid] = st;
    }
    __syncthreads();
#pragma unroll
    for (int j = 0; j < 16; ++j) {
        int b = d_reg[j] >> 8;
        int slot = atomicAdd(&cur[b], 1);
        stage[slot] = ((unsigned int)s_reg[j] << 8) | (unsigned int)(d_reg[j] & 255);
    }
    __syncthreads();
#pragma unroll
    for (int j = 0; j < 16; ++j) {
        int idx = j * 256 + tid;
        pair_buf[blk * EPB + idx] = stage[idx];   // coalesced 4B dump
    }
}

// --- Stage 2: per-bucket padded total + cached per-node counts + dinv.
__global__ __launch_bounds__(512) void csr_sizes_kernel(const unsigned int* __restrict__ pair_buf,
                                                        const int* __restrict__ dir,
                                                        int* __restrict__ bucket_pad,
                                                        int* __restrict__ node_cnt,
                                                        float* __restrict__ dinv,
                                                        int NB, int n) {
    __shared__ int dstart[400];
    __shared__ int dend[400];
    __shared__ int cnt[256];
    int tid = threadIdx.x;
    int b = blockIdx.x;
    for (int i = tid; i < NB; i += 512) {
        dstart[i] = dir[i * DIRW + b];
        dend[i]   = dir[i * DIRW + b + 1];
    }
    if (tid < 256) cnt[tid] = 0;
    __syncthreads();
    int wid = tid >> 6, lane = tid & 63;
    for (int seg = wid; seg < NB; seg += 8) {
        int s0 = dstart[seg], s1 = dend[seg];
        for (int k = s0 + lane; k < s1; k += 64) {
            unsigned int p = pair_buf[(size_t)seg * EPB + k];
            atomicAdd(&cnt[p & 255u], 1);
        }
    }
    __syncthreads();
    if (tid < 256) {
        node_cnt[b * 256 + tid] = cnt[tid];
        int d = b * 256 + tid;
        if (d < n) dinv[d] = rsqrtf((float)(cnt[tid] + 1));   // +1 self loop
    }
    if (tid < 64) {
        int m = max(max(cnt[4 * tid], cnt[4 * tid + 1]),
                    max(cnt[4 * tid + 2], cnt[4 * tid + 3]));
        int L = (m + 7) & ~7;
        int s = L;
#pragma unroll
        for (int off = 1; off < 64; off <<= 1) s += __shfl_xor(s, off);
        if (tid == 0) bucket_pad[b] = 4 * s;
    }
}

// --- Stage 3: place into padded slots (self-scan of bucket_pad; cached
// counts -> no recount). Pads fill with n (zero row). uint16 indices.
__global__ __launch_bounds__(512) void csr_place_kernel(const unsigned int* __restrict__ pair_buf,
                                                        const int* __restrict__ dir,
                                                        const int* __restrict__ bucket_pad,
                                                        const int* __restrict__ node_cnt,
                                                        int* __restrict__ row_ptr,
                                                        unsigned short* __restrict__ csr_src,
                                                        int n, int NB, int nbkt) {
    __shared__ int dstart[400];
    __shared__ int dend[400];
    __shared__ int psc[256];
    __shared__ int Lg[64];
    __shared__ int Lpre[64];
    __shared__ int nbase[256];
    __shared__ int cur[256];
    __shared__ int cend[256];
    int tid = threadIdx.x;
    int b = blockIdx.x;
    for (int i = tid; i < NB; i += 512) {
        dstart[i] = dir[i * DIRW + b];
        dend[i]   = dir[i * DIRW + b + 1];
    }
    if (tid < 256) psc[tid] = (tid < nbkt) ? bucket_pad[tid] : 0;
    __syncthreads();
#pragma unroll
    for (int off = 1; off < 256; off <<= 1) {
        int v = 0;
        if (tid < 256 && tid >= off) v = psc[tid - off];
        __syncthreads();
        if (tid < 256) psc[tid] += v;
        __syncthreads();
    }
    int base = (b > 0) ? psc[b - 1] : 0;
    if (b == nbkt - 1 && tid == 0) row_ptr[n] = psc[nbkt - 1];   // total
    if (tid < 64) {
        int c0 = node_cnt[b * 256 + 4 * tid + 0];
        int c1 = node_cnt[b * 256 + 4 * tid + 1];
        int c2 = node_cnt[b * 256 + 4 * tid + 2];
        int c3 = node_cnt[b * 256 + 4 * tid + 3];
        int m = max(max(c0, c1), max(c2, c3));
        int L = (m + 7) & ~7;
        int x = L;
#pragma unroll
        for (int off = 1; off < 64; off <<= 1) {
            int y = __shfl_up(x, off);
            if (tid >= off) x += y;
        }
        Lg[tid] = L;
        Lpre[tid] = x - L;
    }
    __syncthreads();
    if (tid < 256) {
        int g = tid >> 2;
        int nb = base + 4 * Lpre[g] + (tid & 3) * Lg[g];
        nbase[tid] = nb;
        cur[tid] = nb;
        cend[tid] = nb + Lg[g];
        int d = b * 256 + tid;
        if (d < n) row_ptr[d] = nb;
    }
    __syncthreads();
    int wid = tid >> 6, lane = tid & 63;
    for (int seg = wid; seg < NB; seg += 8) {
        int s0 = dstart[seg], s1 = dend[seg];
        for (int k = s0 + lane; k < s1; k += 64) {
            unsigned int p = pair_buf[(size_t)seg * EPB + k];
            int pos = atomicAdd(&cur[p & 255u], 1);
            csr_src[pos] = (unsigned short)(p >> 8);
        }
    }
    __syncthreads();
    if (tid < 256) {
        for (int pos = cur[tid]; pos < cend[tid]; ++pos)
            csr_src[pos] = (unsigned short)n;   // pad -> zero row
    }
}

// --- MFMA bf16 GEMM + dinv row-scaling epilogue. W pre-transposed bf16 [n][128].
// FP8OUT: H'[r] = e4m3( dinv[r] * (X@W) )  (layers 1,2)
// else:   H'[r] = bf16( dinv[r] * (X@W) )  (layer 3)
template <int NOUT, typename TA, bool FP8OUT>
__global__ __launch_bounds__(256) void gemm_bf16_kernel(const TA* __restrict__ X,
                                                        const unsigned short* __restrict__ Wt,
                                                        const float* __restrict__ dinv,
                                                        void* __restrict__ Hout,
                                                        int n_rows) {
    __shared__ short As[64][136];     // [m][k], 272B stride (16B-aligned rows)
    __shared__ short Bs[NOUT][136];   // [n][k]
    int tid = threadIdx.x;
    int row0 = blockIdx.x * 64;

    {
        int r = tid >> 2;
        int c0 = (tid & 3) * 32;
        int grow = row0 + r;
        if constexpr (std::is_same<TA, float>::value) {
            const float* xp = X + (size_t)grow * 128 + c0;
#pragma unroll
            for (int j = 0; j < 8; ++j) {
                float4 v = (grow < n_rows) ? *(const float4*)(xp + j * 4)
                                           : make_float4(0.f, 0.f, 0.f, 0.f);
                ushort4 p = { f2bf(v.x), f2bf(v.y), f2bf(v.z), f2bf(v.w) };
                *(ushort4*)&As[r][c0 + j * 4] = p;
            }
        } else {
            const unsigned short* xp = X + (size_t)grow * 128 + c0;
#pragma unroll
            for (int j = 0; j < 8; ++j) {
                uint2 v = (grow < n_rows) ? *(const uint2*)(xp + j * 4)
                                          : make_uint2(0u, 0u);
                *(uint2*)&As[r][c0 + j * 4] = v;
            }
        }
    }
    {
        constexpr int TPR = 256 / NOUT;     // threads per row: 2 (N=128) or 4 (N=64)
        constexpr int CH  = 128 / TPR;      // shorts per thread: 64 or 32
        int nrow = tid / TPR;
        int seg  = tid % TPR;
        const unsigned short* wp = Wt + (size_t)nrow * 128 + seg * CH;
#pragma unroll
        for (int j = 0; j < CH / 8; ++j)
            *(uint4*)&Bs[nrow][seg * CH + j * 8] = *(const uint4*)(wp + j * 8);
    }
    __syncthreads();

    int w = tid >> 6, l = tid & 63, lr = l & 15, lg = l >> 4;
    constexpr int NF = NOUT / 16;
    f32x4 acc[NF];
#pragma unroll
    for (int i = 0; i < NF; ++i) acc[i] = (f32x4){0.f, 0.f, 0.f, 0.f};
    int arow = w * 16 + lr;

#pragma unroll
    for (int kc = 0; kc < 128; kc += 32) {
        bf16x8 a;
        ((long long*)&a)[0] = *(const long long*)&As[arow][kc + lg * 4];
        ((long long*)&a)[1] = *(const long long*)&As[arow][kc + 16 + lg * 4];
#pragma unroll
        for (int nf = 0; nf < NF; ++nf) {
            bf16x8 b;
            ((long long*)&b)[0] = *(const long long*)&Bs[nf * 16 + lr][kc + lg * 4];
            ((long long*)&b)[1] = *(const long long*)&Bs[nf * 16 + lr][kc + 16 + lg * 4];
            acc[nf] = __builtin_amdgcn_mfma_f32_16x16x32_bf16(a, b, acc[nf], 0, 0, 0);
        }
    }
    int grow_base = row0 + w * 16 + lg * 4;
    float dv[4];
#pragma unroll
    for (int r = 0; r < 4; ++r)
        dv[r] = (grow_base + r < n_rows) ? dinv[grow_base + r] : 0.f;
#pragma unroll
    for (int nf = 0; nf < NF; ++nf) {
#pragma unroll
        for (int r = 0; r < 4; ++r) {
            int gr = grow_base + r;
            if (gr < n_rows) {
                float val = acc[nf][r] * dv[r];
                if constexpr (FP8OUT) {
                    unsigned int pk = __builtin_amdgcn_cvt_pk_fp8_f32(val, val, 0, false);
                    ((unsigned char*)Hout)[(size_t)gr * NOUT + nf * 16 + lr] =
                        (unsigned char)(pk & 0xFFu);
                } else {
                    ((unsigned short*)Hout)[(size_t)gr * NOUT + nf * 16 + lr] = f2bf(val);
                }
            }
        }
    }
}

// --- Aggregation D=128, fp8 payload: 4 nodes/wave, 16 lanes x uint2 per 128B
// row, x8 unroll; 8 uint16 indices per uint4 load, PREFETCHED one iteration
// ahead (idx load off the gather-dependent chain); HW cvt_pk_f32_fp8 decode.
template <bool RELU>
__global__ __launch_bounds__(256) void agg128_kernel(const unsigned char* __restrict__ H,
                                                     const unsigned short* __restrict__ csr_src,
                                                     const int* __restrict__ row_ptr,
                                                     const float* __restrict__ dinv,
                                                     const float* __restrict__ bias,
                                                     unsigned short* __restrict__ out, int n) {
    int g = blockIdx.x * 4 + threadIdx.y;
    int node0 = g * 4;
    if (node0 >= n) return;
    int lane = threadIdx.x;
    int sub = lane >> 4, l16 = lane & 15;
    int node = node0 + sub;
    int base = row_ptr[node0];
    int L = (row_ptr[node0 + 4] - base) >> 2;
    int e0 = base + sub * L;
    const uint2* H2 = (const uint2*)H;   // 16 uint2 per 128B row
    float acc[8] = {0.f, 0.f, 0.f, 0.f, 0.f, 0.f, 0.f, 0.f};
    if (L > 0) {
        uint4 iv = *(const uint4*)(csr_src + e0);       // first 8 indices
        for (int k = 0; k < L; k += 8) {
            uint4 ivn = (k + 8 < L) ? *(const uint4*)(csr_src + e0 + k + 8) : iv;
            int idx[8] = { (int)(iv.x & 0xFFFFu), (int)(iv.x >> 16),
                           (int)(iv.y & 0xFFFFu), (int)(iv.y >> 16),
                           (int)(iv.z & 0xFFFFu), (int)(iv.z >> 16),
                           (int)(iv.w & 0xFFFFu), (int)(iv.w >> 16) };
            uint2 v[8];
#pragma unroll
            for (int j = 0; j < 8; ++j) v[j] = H2[(size_t)idx[j] * 16 + l16];
#pragma unroll
            for (int j = 0; j < 8; ++j) {
                f32x2 a0 = __builtin_amdgcn_cvt_pk_f32_fp8((int)v[j].x, false);
                f32x2 a1 = __builtin_amdgcn_cvt_pk_f32_fp8((int)v[j].x, true);
                f32x2 a2 = __builtin_amdgcn_cvt_pk_f32_fp8((int)v[j].y, false);
                f32x2 a3 = __builtin_amdgcn_cvt_pk_f32_fp8((int)v[j].y, true);
                acc[0] += a0.x; acc[1] += a0.y; acc[2] += a1.x; acc[3] += a1.y;
                acc[4] += a2.x; acc[5] += a2.y; acc[6] += a3.x; acc[7] += a3.y;
            }
            iv = ivn;
        }
    }
    // self loop (H' already scaled by dinv[node])
    uint2 vn = H2[(size_t)node * 16 + l16];
    {
        f32x2 a0 = __builtin_amdgcn_cvt_pk_f32_fp8((int)vn.x, false);
        f32x2 a1 = __builtin_amdgcn_cvt_pk_f32_fp8((int)vn.x, true);
        f32x2 a2 = __builtin_amdgcn_cvt_pk_f32_fp8((int)vn.y, false);
        f32x2 a3 = __builtin_amdgcn_cvt_pk_f32_fp8((int)vn.y, true);
        acc[0] += a0.x; acc[1] += a0.y; acc[2] += a1.x; acc[3] += a1.y;
        acc[4] += a2.x; acc[5] += a2.y; acc[6] += a3.x; acc[7] += a3.y;
    }
    float dn = dinv[node];
    const float4* b4 = (const float4*)(bias + l16 * 8);
    float4 bb0 = b4[0], bb1 = b4[1];
    float r0 = fmaf(acc[0], dn, bb0.x), r1 = fmaf(acc[1], dn, bb0.y);
    float r2 = fmaf(acc[2], dn, bb0.z), r3 = fmaf(acc[3], dn, bb0.w);
    float r4 = fmaf(acc[4], dn, bb1.x), r5 = fmaf(acc[5], dn, bb1.y);
    float r6 = fmaf(acc[6], dn, bb1.z), r7 = fmaf(acc[7], dn, bb1.w);
    if (RELU) {
        r0 = fmaxf(r0, 0.f); r1 = fmaxf(r1, 0.f); r2 = fmaxf(r2, 0.f); r3 = fmaxf(r3, 0.f);
        r4 = fmaxf(r4, 0.f); r5 = fmaxf(r5, 0.f); r6 = fmaxf(r6, 0.f); r7 = fmaxf(r7, 0.f);
    }
    uint4 pk;
    pk.x = ((unsigned int)f2bf(r1) << 16) | (unsigned int)f2bf(r0);
    pk.y = ((unsigned int)f2bf(r3) << 16) | (unsigned int)f2bf(r2);
    pk.z = ((unsigned int)f2bf(r5) << 16) | (unsigned int)f2bf(r4);
    pk.w = ((unsigned int)f2bf(r7) << 16) | (unsigned int)f2bf(r6);
    ((uint4*)out)[(size_t)node * 16 + l16] = pk;
}

// --- Aggregation D=64 (final): bf16 payload, 4 nodes/wave, uint2, fp32 out;
// idx prefetch one iteration ahead.
__global__ __launch_bounds__(256) void agg64_kernel(const unsigned short* __restrict__ H,
                                                    const unsigned short* __restrict__ csr_src,
                                                    const int* __restrict__ row_ptr,
                                                    const float* __restrict__ dinv,
                                                    const float* __restrict__ bias,
                                                    float* __restrict__ out, int n) {
    int g = blockIdx.x * 4 + threadIdx.y;
    int node0 = g * 4;
    if (node0 >= n) return;
    int lane = threadIdx.x;
    int sub = lane >> 4, l16 = lane & 15;
    int node = node0 + sub;
    int base = row_ptr[node0];
    int L = (row_ptr[node0 + 4] - base) >> 2;
    int e0 = base + sub * L;
    const uint2* H2 = (const uint2*)H;
    float acc[4] = {0.f, 0.f, 0.f, 0.f};
    if (L > 0) {
        uint4 iv = *(const uint4*)(csr_src + e0);       // first 8 indices
        for (int k = 0; k < L; k += 8) {
            uint4 ivn = (k + 8 < L) ? *(const uint4*)(csr_src + e0 + k + 8) : iv;
            int idx[8] = { (int)(iv.x & 0xFFFFu), (int)(iv.x >> 16),
                           (int)(iv.y & 0xFFFFu), (int)(iv.y >> 16),
                           (int)(iv.z & 0xFFFFu), (int)(iv.z >> 16),
                           (int)(iv.w & 0xFFFFu), (int)(iv.w >> 16) };
            uint2 v[8];
#pragma unroll
            for (int j = 0; j < 8; ++j) v[j] = H2[(size_t)idx[j] * 16 + l16];
#pragma unroll
            for (int j = 0; j < 8; ++j) {
                acc[0] += bflo(v[j].x); acc[1] += bfhi(v[j].x);
                acc[2] += bflo(v[j].y); acc[3] += bfhi(v[j].y);
            }
            iv = ivn;
        }
    }
    uint2 vn = H2[(size_t)node * 16 + l16];
    acc[0] += bflo(vn.x); acc[1] += bfhi(vn.x);
    acc[2] += bflo(vn.y); acc[3] += bfhi(vn.y);
    float dn = dinv[node];
    float4 bb = *(const float4*)(bias + l16 * 4);
    float4 r;
    r.x = fmaf(acc[0], dn, bb.x);
    r.y = fmaf(acc[1], dn, bb.y);
    r.z = fmaf(acc[2], dn, bb.z);
    r.w = fmaf(acc[3], dn, bb.w);
    *(float4*)(out + (size_t)node * 64 + l16 * 4) = r;
}

extern "C" void kernel_launch(void* const* d_in, const int* in_sizes, int n_in,
                              void* d_out, int out_size, void* d_ws, size_t ws_size,
                              hipStream_t stream) {
    const float* x  = (const float*)d_in[0];
    const int*   ei = (const int*)d_in[1];
    const float* W1 = (const float*)d_in[2];
    const float* b1 = (const float*)d_in[3];
    const float* W2 = (const float*)d_in[4];
    const float* b2 = (const float*)d_in[5];
    const float* W3 = (const float*)d_in[6];
    const float* b3 = (const float*)d_in[7];

    const int n = in_sizes[0] / 128;   // 50000 (divisible by 4, < 65536)
    const int E = in_sizes[1] / 2;     // 1600000
    const int* src = ei;
    const int* dst = ei + E;
    const int nbkt = (n + 255) >> 8;           // 196
    const int NB = (E + EPB - 1) / EPB;        // 391

    char* ws = (char*)d_ws;
    size_t off = 0;
    auto alloc = [&](size_t bytes) {
        void* p = ws + off;
        off = (off + bytes + 511) & ~(size_t)511;
        return p;
    };
    int*   bucket_pad  = (int*)alloc(256 * 4);
    int*   row_ptr     = (int*)alloc((size_t)(n + 1) * 4);
    float* dinv        = (float*)alloc((size_t)n * 4);
    int*   node_cnt    = (int*)alloc((size_t)nbkt * 256 * 4);
    unsigned short* csr_src = (unsigned short*)alloc((size_t)4000000 * 2);  // padded CSR (~2.1M used)
    unsigned short* Wt1 = (unsigned short*)alloc(128 * 128 * 2);
    unsigned short* Wt2 = (unsigned short*)alloc(128 * 128 * 2);
    unsigned short* Wt3 = (unsigned short*)alloc(64 * 128 * 2);
    // Hb: layers 1,2 = (n+1) x 128 fp8 bytes; layer 3 = (n+1) x 64 bf16 = same
    // byte footprint (row i at byte i*128 in both layouts; zero row n shared).
    unsigned char* Hb  = (unsigned char*)alloc((size_t)(n + 1) * 128);
    unsigned short* Bb = (unsigned short*)alloc((size_t)n * 128 * 2);
    // pair_buf (NB*EPB uint = 6.4MB) + dir (308KB) alias Bb: dead after
    // csr_place; Bb first written by agg1 (after csr_place completes).
    unsigned int* pair_buf = (unsigned int*)Bb;
    int*          dir      = (int*)((char*)Bb + (size_t)NB * EPB * 4);
    (void)ws_size;

    bin_wtrans_kernel<<<NB + 160, 256, 0, stream>>>(src, dst, pair_buf, dir, E, nbkt, NB,
                                                    W1, W2, W3, Wt1, Wt2, Wt3,
                                                    (unsigned int*)(Hb + (size_t)n * 128));
    csr_sizes_kernel<<<nbkt, 512, 0, stream>>>(pair_buf, dir, bucket_pad, node_cnt, dinv, NB, n);
    csr_place_kernel<<<nbkt, 512, 0, stream>>>(pair_buf, dir, bucket_pad, node_cnt,
                                               row_ptr, csr_src, n, NB, nbkt);

    dim3 aggBlock(64, 4);
    int aggGrid = (n / 4 + 3) / 4;     // 4 nodes/wave, 4 waves/block
    int gemmGrid = (n + 63) / 64;

    // layer 1 (fp8 H)
    gemm_bf16_kernel<128, float, true><<<gemmGrid, 256, 0, stream>>>(x, Wt1, dinv, Hb, n);
    agg128_kernel<true><<<aggGrid, aggBlock, 0, stream>>>(Hb, csr_src, row_ptr, dinv, b1, Bb, n);
    // layer 2 (fp8 H)
    gemm_bf16_kernel<128, unsigned short, true><<<gemmGrid, 256, 0, stream>>>(Bb, Wt2, dinv, Hb, n);
    agg128_kernel<true><<<aggGrid, aggBlock, 0, stream>>>(Hb, csr_src, row_ptr, dinv, b2, Bb, n);
    // layer 3 (bf16 H, 64-wide, fp32 out)
    gemm_bf16_kernel<64, unsigned short, false><<<gemmGrid, 256, 0, stream>>>(Bb, Wt3, dinv, Hb, n);
    agg64_kernel<<<aggGrid, aggBlock, 0, stream>>>((unsigned short*)Hb, csr_src, row_ptr,
                                                   dinv, b3, (float*)d_out, n);
}

// Round 15
// 188.930 us; speedup vs baseline: 1.1519x; 1.1519x over previous
//
#include <hip/hip_runtime.h>
#include <type_traits>

// ---------------------------------------------------------------------------
// 3-layer GCN, mixed-precision H pipeline with dinv pre-scaling:
//   GEMM (MFMA bf16, fp32 accum) epilogue scales row r by dinv[r]:
//     layers 1,2 -> H' stored FP8 e4m3 (6.4MB gather payload);
//     layer 3 -> H' bf16 (error budget: L3 noise only attenuated once).
//   agg: out[d] = dinv[d]*( sum_e H'[s] + H'[d] ) + b
// Aggregation: 4 nodes/wave (16 lanes/row), padded slots (pad -> zero row n),
// x8 unroll, uint16 indices loaded 8-at-a-time (slot bases are 8-aligned),
// HW cvt_pk_f32_fp8 decode.
// BEST-KNOWN CONFIGURATION (round 12, 189.2us). Four refinements tried and
// REVERTED with measured regressions: per-node sort (123us kernel cost),
// src-range partition (+19us: waves unsynchronized, pad overhead certain),
// agg+gemm fusion (52KB LDS -> 18% occupancy -> gather lost latency hiding),
// idx prefetch (+28us: broke memory-clause formation, added live state).
// The agg gather sits at its compulsory per-XCD replication floor
// (fp8 H: 6.4MB x 8 XCDs ~= 51MB/agg, confirmed by fused-kernel FETCH).
// 9 dispatches: bin+wtrans+padzero | sizes | place(self-scan) | 3x(gemm,agg).
// ---------------------------------------------------------------------------

#define EPB  4096   // edges per bin block
#define DIRW 197    // directory row width = max buckets (50176/256) + 1

typedef __attribute__((ext_vector_type(8))) short bf16x8;
typedef __attribute__((ext_vector_type(4))) float f32x4;
typedef __attribute__((ext_vector_type(2))) float f32x2;

__device__ __forceinline__ unsigned short f2bf(float f) {
    unsigned int u = __float_as_uint(f);
    u += 0x7FFFu + ((u >> 16) & 1u);   // round-to-nearest-even
    return (unsigned short)(u >> 16);
}
__device__ __forceinline__ float bflo(unsigned int u) { return __uint_as_float(u << 16); }
__device__ __forceinline__ float bfhi(unsigned int u) { return __uint_as_float(u & 0xFFFF0000u); }

// --- Stage 1 (fused): blocks [0,NB) bucket-sort edges; blocks [NB,NB+160)
// pre-transpose W fp32 [k][n] -> bf16 [n][128]; block NB also zeroes pad row.
__global__ __launch_bounds__(256) void bin_wtrans_kernel(const int* __restrict__ src,
                                                         const int* __restrict__ dst,
                                                         unsigned int* __restrict__ pair_buf,
                                                         int* __restrict__ dir,
                                                         int E, int nbkt, int NB,
                                                         const float* __restrict__ W1,
                                                         const float* __restrict__ W2,
                                                         const float* __restrict__ W3,
                                                         unsigned short* __restrict__ Wt1,
                                                         unsigned short* __restrict__ Wt2,
                                                         unsigned short* __restrict__ Wt3,
                                                         unsigned int* __restrict__ hb_pad_row) {
    int blk = blockIdx.x;
    if (blk >= NB) {
        int wb = blk - NB;
        const float* W; unsigned short* Wt; int N, e0;
        if (wb < 64)       { W = W1; Wt = Wt1; N = 128; e0 = wb * 256; }
        else if (wb < 128) { W = W2; Wt = Wt2; N = 128; e0 = (wb - 64) * 256; }
        else               { W = W3; Wt = Wt3; N = 64;  e0 = (wb - 128) * 256; }
        int e = e0 + threadIdx.x;          // output-linear: e = nn*128 + k
        int nn = e >> 7, k = e & 127;
        Wt[e] = f2bf(W[(size_t)k * N + nn]);
        if (wb == 0 && threadIdx.x < 32) hb_pad_row[threadIdx.x] = 0u;  // 128B zero row
        return;
    }
    __shared__ unsigned int stage[EPB];  // 16 KB
    __shared__ int hist[DIRW];
    __shared__ int sc[256];
    __shared__ int cur[DIRW];
    int tid = threadIdx.x;
    if (tid < DIRW) hist[tid] = 0;
    __syncthreads();

    int s_reg[16], d_reg[16];
#pragma unroll
    for (int j = 0; j < 16; ++j) {
        int gi = blk * EPB + j * 256 + tid;
        int s = 0, d = nbkt << 8;          // invalid -> trash bucket nbkt
        if (gi < E) { s = src[gi]; d = dst[gi]; }
        s_reg[j] = s; d_reg[j] = d;
        atomicAdd(&hist[d >> 8], 1);
    }
    __syncthreads();
    int h = (tid < DIRW) ? hist[tid] : 0;
    sc[tid] = h;
    __syncthreads();
#pragma unroll
    for (int off = 1; off < 256; off <<= 1) {
        int v = (tid >= off) ? sc[tid - off] : 0;
        __syncthreads();
        sc[tid] += v;
        __syncthreads();
    }
    if (tid < DIRW) {
        int st = sc[tid] - h;
        cur[tid] = st;
        dir[blk * DIRW + tid] = st;
    }
    __syncthreads();
#pragma unroll
    for (int j = 0; j < 16; ++j) {
        int b = d_reg[j] >> 8;
        int slot = atomicAdd(&cur[b], 1);
        stage[slot] = ((unsigned int)s_reg[j] << 8) | (unsigned int)(d_reg[j] & 255);
    }
    __syncthreads();
#pragma unroll
    for (int j = 0; j < 16; ++j) {
        int idx = j * 256 + tid;
        pair_buf[blk * EPB + idx] = stage[idx];   // coalesced 4B dump
    }
}

// --- Stage 2: per-bucket padded total + cached per-node counts + dinv.
__global__ __launch_bounds__(512) void csr_sizes_kernel(const unsigned int* __restrict__ pair_buf,
                                                        const int* __restrict__ dir,
                                                        int* __restrict__ bucket_pad,
                                                        int* __restrict__ node_cnt,
                                                        float* __restrict__ dinv,
                                                        int NB, int n) {
    __shared__ int dstart[400];
    __shared__ int dend[400];
    __shared__ int cnt[256];
    int tid = threadIdx.x;
    int b = blockIdx.x;
    for (int i = tid; i < NB; i += 512) {
        dstart[i] = dir[i * DIRW + b];
        dend[i]   = dir[i * DIRW + b + 1];
    }
    if (tid < 256) cnt[tid] = 0;
    __syncthreads();
    int wid = tid >> 6, lane = tid & 63;
    for (int seg = wid; seg < NB; seg += 8) {
        int s0 = dstart[seg], s1 = dend[seg];
        for (int k = s0 + lane; k < s1; k += 64) {
            unsigned int p = pair_buf[(size_t)seg * EPB + k];
            atomicAdd(&cnt[p & 255u], 1);
        }
    }
    __syncthreads();
    if (tid < 256) {
        node_cnt[b * 256 + tid] = cnt[tid];
        int d = b * 256 + tid;
        if (d < n) dinv[d] = rsqrtf((float)(cnt[tid] + 1));   // +1 self loop
    }
    if (tid < 64) {
        int m = max(max(cnt[4 * tid], cnt[4 * tid + 1]),
                    max(cnt[4 * tid + 2], cnt[4 * tid + 3]));
        int L = (m + 7) & ~7;
        int s = L;
#pragma unroll
        for (int off = 1; off < 64; off <<= 1) s += __shfl_xor(s, off);
        if (tid == 0) bucket_pad[b] = 4 * s;
    }
}

// --- Stage 3: place into padded slots (self-scan of bucket_pad; cached
// counts -> no recount). Pads fill with n (zero row). uint16 indices.
__global__ __launch_bounds__(512) void csr_place_kernel(const unsigned int* __restrict__ pair_buf,
                                                        const int* __restrict__ dir,
                                                        const int* __restrict__ bucket_pad,
                                                        const int* __restrict__ node_cnt,
                                                        int* __restrict__ row_ptr,
                                                        unsigned short* __restrict__ csr_src,
                                                        int n, int NB, int nbkt) {
    __shared__ int dstart[400];
    __shared__ int dend[400];
    __shared__ int psc[256];
    __shared__ int Lg[64];
    __shared__ int Lpre[64];
    __shared__ int nbase[256];
    __shared__ int cur[256];
    __shared__ int cend[256];
    int tid = threadIdx.x;
    int b = blockIdx.x;
    for (int i = tid; i < NB; i += 512) {
        dstart[i] = dir[i * DIRW + b];
        dend[i]   = dir[i * DIRW + b + 1];
    }
    if (tid < 256) psc[tid] = (tid < nbkt) ? bucket_pad[tid] : 0;
    __syncthreads();
#pragma unroll
    for (int off = 1; off < 256; off <<= 1) {
        int v = 0;
        if (tid < 256 && tid >= off) v = psc[tid - off];
        __syncthreads();
        if (tid < 256) psc[tid] += v;
        __syncthreads();
    }
    int base = (b > 0) ? psc[b - 1] : 0;
    if (b == nbkt - 1 && tid == 0) row_ptr[n] = psc[nbkt - 1];   // total
    if (tid < 64) {
        int c0 = node_cnt[b * 256 + 4 * tid + 0];
        int c1 = node_cnt[b * 256 + 4 * tid + 1];
        int c2 = node_cnt[b * 256 + 4 * tid + 2];
        int c3 = node_cnt[b * 256 + 4 * tid + 3];
        int m = max(max(c0, c1), max(c2, c3));
        int L = (m + 7) & ~7;
        int x = L;
#pragma unroll
        for (int off = 1; off < 64; off <<= 1) {
            int y = __shfl_up(x, off);
            if (tid >= off) x += y;
        }
        Lg[tid] = L;
        Lpre[tid] = x - L;
    }
    __syncthreads();
    if (tid < 256) {
        int g = tid >> 2;
        int nb = base + 4 * Lpre[g] + (tid & 3) * Lg[g];
        nbase[tid] = nb;
        cur[tid] = nb;
        cend[tid] = nb + Lg[g];
        int d = b * 256 + tid;
        if (d < n) row_ptr[d] = nb;
    }
    __syncthreads();
    int wid = tid >> 6, lane = tid & 63;
    for (int seg = wid; seg < NB; seg += 8) {
        int s0 = dstart[seg], s1 = dend[seg];
        for (int k = s0 + lane; k < s1; k += 64) {
            unsigned int p = pair_buf[(size_t)seg * EPB + k];
            int pos = atomicAdd(&cur[p & 255u], 1);
            csr_src[pos] = (unsigned short)(p >> 8);
        }
    }
    __syncthreads();
    if (tid < 256) {
        for (int pos = cur[tid]; pos < cend[tid]; ++pos)
            csr_src[pos] = (unsigned short)n;   // pad -> zero row
    }
}

// --- MFMA bf16 GEMM + dinv row-scaling epilogue. W pre-transposed bf16 [n][128].
// FP8OUT: H'[r] = e4m3( dinv[r] * (X@W) )  (layers 1,2)
// else:   H'[r] = bf16( dinv[r] * (X@W) )  (layer 3)
template <int NOUT, typename TA, bool FP8OUT>
__global__ __launch_bounds__(256) void gemm_bf16_kernel(const TA* __restrict__ X,
                                                        const unsigned short* __restrict__ Wt,
                                                        const float* __restrict__ dinv,
                                                        void* __restrict__ Hout,
                                                        int n_rows) {
    __shared__ short As[64][136];     // [m][k], 272B stride (16B-aligned rows)
    __shared__ short Bs[NOUT][136];   // [n][k]
    int tid = threadIdx.x;
    int row0 = blockIdx.x * 64;

    {
        int r = tid >> 2;
        int c0 = (tid & 3) * 32;
        int grow = row0 + r;
        if constexpr (std::is_same<TA, float>::value) {
            const float* xp = X + (size_t)grow * 128 + c0;
#pragma unroll
            for (int j = 0; j < 8; ++j) {
                float4 v = (grow < n_rows) ? *(const float4*)(xp + j * 4)
                                           : make_float4(0.f, 0.f, 0.f, 0.f);
                ushort4 p = { f2bf(v.x), f2bf(v.y), f2bf(v.z), f2bf(v.w) };
                *(ushort4*)&As[r][c0 + j * 4] = p;
            }
        } else {
            const unsigned short* xp = X + (size_t)grow * 128 + c0;
#pragma unroll
            for (int j = 0; j < 8; ++j) {
                uint2 v = (grow < n_rows) ? *(const uint2*)(xp + j * 4)
                                          : make_uint2(0u, 0u);
                *(uint2*)&As[r][c0 + j * 4] = v;
            }
        }
    }
    {
        constexpr int TPR = 256 / NOUT;     // threads per row: 2 (N=128) or 4 (N=64)
        constexpr int CH  = 128 / TPR;      // shorts per thread: 64 or 32
        int nrow = tid / TPR;
        int seg  = tid % TPR;
        const unsigned short* wp = Wt + (size_t)nrow * 128 + seg * CH;
#pragma unroll
        for (int j = 0; j < CH / 8; ++j)
            *(uint4*)&Bs[nrow][seg * CH + j * 8] = *(const uint4*)(wp + j * 8);
    }
    __syncthreads();

    int w = tid >> 6, l = tid & 63, lr = l & 15, lg = l >> 4;
    constexpr int NF = NOUT / 16;
    f32x4 acc[NF];
#pragma unroll
    for (int i = 0; i < NF; ++i) acc[i] = (f32x4){0.f, 0.f, 0.f, 0.f};
    int arow = w * 16 + lr;

#pragma unroll
    for (int kc = 0; kc < 128; kc += 32) {
        bf16x8 a;
        ((long long*)&a)[0] = *(const long long*)&As[arow][kc + lg * 4];
        ((long long*)&a)[1] = *(const long long*)&As[arow][kc + 16 + lg * 4];
#pragma unroll
        for (int nf = 0; nf < NF; ++nf) {
            bf16x8 b;
            ((long long*)&b)[0] = *(const long long*)&Bs[nf * 16 + lr][kc + lg * 4];
            ((long long*)&b)[1] = *(const long long*)&Bs[nf * 16 + lr][kc + 16 + lg * 4];
            acc[nf] = __builtin_amdgcn_mfma_f32_16x16x32_bf16(a, b, acc[nf], 0, 0, 0);
        }
    }
    int grow_base = row0 + w * 16 + lg * 4;
    float dv[4];
#pragma unroll
    for (int r = 0; r < 4; ++r)
        dv[r] = (grow_base + r < n_rows) ? dinv[grow_base + r] : 0.f;
#pragma unroll
    for (int nf = 0; nf < NF; ++nf) {
#pragma unroll
        for (int r = 0; r < 4; ++r) {
            int gr = grow_base + r;
            if (gr < n_rows) {
                float val = acc[nf][r] * dv[r];
                if constexpr (FP8OUT) {
                    unsigned int pk = __builtin_amdgcn_cvt_pk_fp8_f32(val, val, 0, false);
                    ((unsigned char*)Hout)[(size_t)gr * NOUT + nf * 16 + lr] =
                        (unsigned char)(pk & 0xFFu);
                } else {
                    ((unsigned short*)Hout)[(size_t)gr * NOUT + nf * 16 + lr] = f2bf(val);
                }
            }
        }
    }
}

// --- Aggregation D=128, fp8 payload: 4 nodes/wave, 16 lanes x uint2 per 128B
// row, x8 unroll; 8 uint16 indices per uint4 load (slot bases 8-aligned);
// HW cvt_pk_f32_fp8 decode; bf16 output.
template <bool RELU>
__global__ __launch_bounds__(256) void agg128_kernel(const unsigned char* __restrict__ H,
                                                     const unsigned short* __restrict__ csr_src,
                                                     const int* __restrict__ row_ptr,
                                                     const float* __restrict__ dinv,
                                                     const float* __restrict__ bias,
                                                     unsigned short* __restrict__ out, int n) {
    int g = blockIdx.x * 4 + threadIdx.y;
    int node0 = g * 4;
    if (node0 >= n) return;
    int lane = threadIdx.x;
    int sub = lane >> 4, l16 = lane & 15;
    int node = node0 + sub;
    int base = row_ptr[node0];
    int L = (row_ptr[node0 + 4] - base) >> 2;
    int e0 = base + sub * L;
    const uint2* H2 = (const uint2*)H;   // 16 uint2 per 128B row
    float acc[8] = {0.f, 0.f, 0.f, 0.f, 0.f, 0.f, 0.f, 0.f};
    for (int k = 0; k < L; k += 8) {
        uint4 iv = *(const uint4*)(csr_src + e0 + k);   // 8 uint16 indices
        int idx[8] = { (int)(iv.x & 0xFFFFu), (int)(iv.x >> 16),
                       (int)(iv.y & 0xFFFFu), (int)(iv.y >> 16),
                       (int)(iv.z & 0xFFFFu), (int)(iv.z >> 16),
                       (int)(iv.w & 0xFFFFu), (int)(iv.w >> 16) };
        uint2 v[8];
#pragma unroll
        for (int j = 0; j < 8; ++j) v[j] = H2[(size_t)idx[j] * 16 + l16];
#pragma unroll
        for (int j = 0; j < 8; ++j) {
            f32x2 a0 = __builtin_amdgcn_cvt_pk_f32_fp8((int)v[j].x, false);
            f32x2 a1 = __builtin_amdgcn_cvt_pk_f32_fp8((int)v[j].x, true);
            f32x2 a2 = __builtin_amdgcn_cvt_pk_f32_fp8((int)v[j].y, false);
            f32x2 a3 = __builtin_amdgcn_cvt_pk_f32_fp8((int)v[j].y, true);
            acc[0] += a0.x; acc[1] += a0.y; acc[2] += a1.x; acc[3] += a1.y;
            acc[4] += a2.x; acc[5] += a2.y; acc[6] += a3.x; acc[7] += a3.y;
        }
    }
    // self loop (H' already scaled by dinv[node])
    uint2 vn = H2[(size_t)node * 16 + l16];
    {
        f32x2 a0 = __builtin_amdgcn_cvt_pk_f32_fp8((int)vn.x, false);
        f32x2 a1 = __builtin_amdgcn_cvt_pk_f32_fp8((int)vn.x, true);
        f32x2 a2 = __builtin_amdgcn_cvt_pk_f32_fp8((int)vn.y, false);
        f32x2 a3 = __builtin_amdgcn_cvt_pk_f32_fp8((int)vn.y, true);
        acc[0] += a0.x; acc[1] += a0.y; acc[2] += a1.x; acc[3] += a1.y;
        acc[4] += a2.x; acc[5] += a2.y; acc[6] += a3.x; acc[7] += a3.y;
    }
    float dn = dinv[node];
    const float4* b4 = (const float4*)(bias + l16 * 8);
    float4 bb0 = b4[0], bb1 = b4[1];
    float r0 = fmaf(acc[0], dn, bb0.x), r1 = fmaf(acc[1], dn, bb0.y);
    float r2 = fmaf(acc[2], dn, bb0.z), r3 = fmaf(acc[3], dn, bb0.w);
    float r4 = fmaf(acc[4], dn, bb1.x), r5 = fmaf(acc[5], dn, bb1.y);
    float r6 = fmaf(acc[6], dn, bb1.z), r7 = fmaf(acc[7], dn, bb1.w);
    if (RELU) {
        r0 = fmaxf(r0, 0.f); r1 = fmaxf(r1, 0.f); r2 = fmaxf(r2, 0.f); r3 = fmaxf(r3, 0.f);
        r4 = fmaxf(r4, 0.f); r5 = fmaxf(r5, 0.f); r6 = fmaxf(r6, 0.f); r7 = fmaxf(r7, 0.f);
    }
    uint4 pk;
    pk.x = ((unsigned int)f2bf(r1) << 16) | (unsigned int)f2bf(r0);
    pk.y = ((unsigned int)f2bf(r3) << 16) | (unsigned int)f2bf(r2);
    pk.z = ((unsigned int)f2bf(r5) << 16) | (unsigned int)f2bf(r4);
    pk.w = ((unsigned int)f2bf(r7) << 16) | (unsigned int)f2bf(r6);
    ((uint4*)out)[(size_t)node * 16 + l16] = pk;
}

// --- Aggregation D=64 (final): bf16 payload, 4 nodes/wave, uint2, fp32 out.
__global__ __launch_bounds__(256) void agg64_kernel(const unsigned short* __restrict__ H,
                                                    const unsigned short* __restrict__ csr_src,
                                                    const int* __restrict__ row_ptr,
                                                    const float* __restrict__ dinv,
                                                    const float* __restrict__ bias,
                                                    float* __restrict__ out, int n) {
    int g = blockIdx.x * 4 + threadIdx.y;
    int node0 = g * 4;
    if (node0 >= n) return;
    int lane = threadIdx.x;
    int sub = lane >> 4, l16 = lane & 15;
    int node = node0 + sub;
    int base = row_ptr[node0];
    int L = (row_ptr[node0 + 4] - base) >> 2;
    int e0 = base + sub * L;
    const uint2* H2 = (const uint2*)H;
    float acc[4] = {0.f, 0.f, 0.f, 0.f};
    for (int k = 0; k < L; k += 8) {
        uint4 iv = *(const uint4*)(csr_src + e0 + k);   // 8 uint16 indices
        int idx[8] = { (int)(iv.x & 0xFFFFu), (int)(iv.x >> 16),
                       (int)(iv.y & 0xFFFFu), (int)(iv.y >> 16),
                       (int)(iv.z & 0xFFFFu), (int)(iv.z >> 16),
                       (int)(iv.w & 0xFFFFu), (int)(iv.w >> 16) };
        uint2 v[8];
#pragma unroll
        for (int j = 0; j < 8; ++j) v[j] = H2[(size_t)idx[j] * 16 + l16];
#pragma unroll
        for (int j = 0; j < 8; ++j) {
            acc[0] += bflo(v[j].x); acc[1] += bfhi(v[j].x);
            acc[2] += bflo(v[j].y); acc[3] += bfhi(v[j].y);
        }
    }
    uint2 vn = H2[(size_t)node * 16 + l16];
    acc[0] += bflo(vn.x); acc[1] += bfhi(vn.x);
    acc[2] += bflo(vn.y); acc[3] += bfhi(vn.y);
    float dn = dinv[node];
    float4 bb = *(const float4*)(bias + l16 * 4);
    float4 r;
    r.x = fmaf(acc[0], dn, bb.x);
    r.y = fmaf(acc[1], dn, bb.y);
    r.z = fmaf(acc[2], dn, bb.z);
    r.w = fmaf(acc[3], dn, bb.w);
    *(float4*)(out + (size_t)node * 64 + l16 * 4) = r;
}

extern "C" void kernel_launch(void* const* d_in, const int* in_sizes, int n_in,
                              void* d_out, int out_size, void* d_ws, size_t ws_size,
                              hipStream_t stream) {
    const float* x  = (const float*)d_in[0];
    const int*   ei = (const int*)d_in[1];
    const float* W1 = (const float*)d_in[2];
    const float* b1 = (const float*)d_in[3];
    const float* W2 = (const float*)d_in[4];
    const float* b2 = (const float*)d_in[5];
    const float* W3 = (const float*)d_in[6];
    const float* b3 = (const float*)d_in[7];

    const int n = in_sizes[0] / 128;   // 50000 (divisible by 4, < 65536)
    const int E = in_sizes[1] / 2;     // 1600000
    const int* src = ei;
    const int* dst = ei + E;
    const int nbkt = (n + 255) >> 8;           // 196
    const int NB = (E + EPB - 1) / EPB;        // 391

    char* ws = (char*)d_ws;
    size_t off = 0;
    auto alloc = [&](size_t bytes) {
        void* p = ws + off;
        off = (off + bytes + 511) & ~(size_t)511;
        return p;
    };
    int*   bucket_pad  = (int*)alloc(256 * 4);
    int*   row_ptr     = (int*)alloc((size_t)(n + 1) * 4);
    float* dinv        = (float*)alloc((size_t)n * 4);
    int*   node_cnt    = (int*)alloc((size_t)nbkt * 256 * 4);
    unsigned short* csr_src = (unsigned short*)alloc((size_t)4000000 * 2);  // padded CSR (~2.1M used)
    unsigned short* Wt1 = (unsigned short*)alloc(128 * 128 * 2);
    unsigned short* Wt2 = (unsigned short*)alloc(128 * 128 * 2);
    unsigned short* Wt3 = (unsigned short*)alloc(64 * 128 * 2);
    // Hb: layers 1,2 = (n+1) x 128 fp8 bytes; layer 3 = (n+1) x 64 bf16 = same
    // byte footprint (row i at byte i*128 in both layouts; zero row n shared).
    unsigned char* Hb  = (unsigned char*)alloc((size_t)(n + 1) * 128);
    unsigned short* Bb = (unsigned short*)alloc((size_t)n * 128 * 2);
    // pair_buf (NB*EPB uint = 6.4MB) + dir (308KB) alias Bb: dead after
    // csr_place; Bb first written by agg1 (after csr_place completes).
    unsigned int* pair_buf = (unsigned int*)Bb;
    int*          dir      = (int*)((char*)Bb + (size_t)NB * EPB * 4);
    (void)ws_size;

    bin_wtrans_kernel<<<NB + 160, 256, 0, stream>>>(src, dst, pair_buf, dir, E, nbkt, NB,
                                                    W1, W2, W3, Wt1, Wt2, Wt3,
                                                    (unsigned int*)(Hb + (size_t)n * 128));
    csr_sizes_kernel<<<nbkt, 512, 0, stream>>>(pair_buf, dir, bucket_pad, node_cnt, dinv, NB, n);
    csr_place_kernel<<<nbkt, 512, 0, stream>>>(pair_buf, dir, bucket_pad, node_cnt,
                                               row_ptr, csr_src, n, NB, nbkt);

    dim3 aggBlock(64, 4);
    int aggGrid = (n / 4 + 3) / 4;     // 4 nodes/wave, 4 waves/block
    int gemmGrid = (n + 63) / 64;

    // layer 1 (fp8 H)
    gemm_bf16_kernel<128, float, true><<<gemmGrid, 256, 0, stream>>>(x, Wt1, dinv, Hb, n);
    agg128_kernel<true><<<aggGrid, aggBlock, 0, stream>>>(Hb, csr_src, row_ptr, dinv, b1, Bb, n);
    // layer 2 (fp8 H)
    gemm_bf16_kernel<128, unsigned short, true><<<gemmGrid, 256, 0, stream>>>(Bb, Wt2, dinv, Hb, n);
    agg128_kernel<true><<<aggGrid, aggBlock, 0, stream>>>(Hb, csr_src, row_ptr, dinv, b2, Bb, n);
    // layer 3 (bf16 H, 64-wide, fp32 out)
    gemm_bf16_kernel<64, unsigned short, false><<<gemmGrid, 256, 0, stream>>>(Bb, Wt3, dinv, Hb, n);
    agg64_kernel<<<aggGrid, aggBlock, 0, stream>>>((unsigned short*)Hb, csr_src, row_ptr,
                                                   dinv, b3, (float*)d_out, n);
}